// Round 15
// baseline (383.814 us; speedup 1.0000x reference)
//
#include <hip/hip_runtime.h>
#include <hip/hip_bf16.h>
#include <cstdint>
#include <cstddef>

#define B_    64
#define N_    2048
#define E_    32768            // edges per graph
#define DIM_  64
#define K1_   1639
#define K2_   1312
#define NTOT  (B_ * N_)        // 131072
#define ETOT  (B_ * E_)        // 2097152
#define N2TOT (B_ * K1_)       // 104896
#define NCLS  6
#define PB_   8                // pooling blocks per graph
#define CHUNKS_ 16             // dst-chunks per graph
#define SLICES_ 16             // edge slices per graph in k_bucket
#define BCAP  3072             // bucket capacity (= SLICES_*REG_)
#define REG_  192              // per-slice region (mean 128, sd ~11 -> +5.8 sigma)
#define T2_   26               // stage-2 tiles/graph (26*64 = 1664 >= 1639)

typedef short bf8 __attribute__((ext_vector_type(8)));
typedef float f4  __attribute__((ext_vector_type(4)));

static __device__ __forceinline__ float2 bf2f(unsigned u) {
    float2 r;
    r.x = __uint_as_float(u << 16);
    r.y = __uint_as_float(u & 0xFFFF0000u);
    return r;
}
static __device__ __forceinline__ unsigned f2bf(float a, float b) {
    __hip_bfloat162 h = __float22bfloat162_rn(make_float2(a, b));
    unsigned u;
    __builtin_memcpy(&u, &h, 4);
    return u;
}
static __device__ __forceinline__ unsigned short f2bf_rn(float v) {
    unsigned u = __float_as_uint(v);
    return (unsigned short)((u + 0x7FFFu + ((u >> 16) & 1u)) >> 16);
}

// ---------------- bucket edges by (graph, dst-chunk) into slice-owned regions --------------
template<int STAGE>
__launch_bounds__(256)
__global__ void k_bucket(const int* src, const int* dst, const int* remap,
                         int* bcnt, unsigned int* blist) {
    const int LSTR = (STAGE == 1) ? 128 : 103;
    __shared__ unsigned int lb[CHUNKS_][REG_];
    __shared__ int lc[CHUNKS_];
    __shared__ int rm[N_];                     // stage2 only
    int b = blockIdx.x;
    int g = b & 63, slice = b >> 6;
    int tid = threadIdx.x;
    if (tid < CHUNKS_) lc[tid] = 0;
    if (STAGE == 2)
        for (int i = tid; i < N_; i += 256) rm[i] = remap[g * N_ + i];
    __syncthreads();
    const int ESL = E_ / SLICES_;              // 2048
    const int* sp = src + (size_t)g * E_ + slice * ESL;
    const int* dp = dst + (size_t)g * E_ + slice * ESL;
    int gbase = g * ((STAGE == 1) ? N_ : K1_);
    for (int e = tid * 4; e < ESL; e += 1024) {
        int4 ss = *(const int4*)&sp[e];
        int4 dd = *(const int4*)&dp[e];
#pragma unroll
        for (int t = 0; t < 4; t++) {
            int s = (&ss.x)[t], d = (&dd.x)[t];
            if (STAGE == 2) {
                s = rm[s & (N_ - 1)]; d = rm[d & (N_ - 1)];
                if ((s | d) < 0) continue;     // edge touches a dropped node
                s -= gbase; d -= gbase;
            } else {
                s &= (N_ - 1); d &= (N_ - 1);
            }
            int ch = d / LSTR;
            int dl = d - ch * LSTR;
            int p = atomicAdd(&lc[ch], 1);
            if (p < REG_) lb[ch][p] = ((unsigned)dl << 12) | (unsigned)s;
        }
    }
    __syncthreads();
    for (int ch = 0; ch < CHUNKS_; ch++) {
        int n = min(lc[ch], REG_);
        unsigned int* out = blist + (size_t)(g * CHUNKS_ + ch) * BCAP + slice * REG_;
        for (int i = tid; i < n; i += 256) out[i] = lb[ch][i];
    }
    if (tid < CHUNKS_) bcnt[(g * SLICES_ + slice) * CHUNKS_ + tid] = min(lc[tid], REG_);
}

// ---------------- counting-sort -> in-place compact CSR (pre-shifted) + ninfo + prescale ----
template<int STAGE>
__launch_bounds__(256)
__global__ void k_sort(const int* bcnt, unsigned int* blist,
                       const float* xf, const unsigned int* xg,
                       unsigned int* xb, int* ninfo) {
    const int NL   = (STAGE == 1) ? N_ : K1_;
    const int LSTR = (STAGE == 1) ? 128 : 103;
    __shared__ int cnt[128], st[128], cur[128], cnt_s[SLICES_], stot[2];
    __shared__ float rsqv[128];
    __shared__ unsigned short sorted[BCAP];
    int b = blockIdx.x;
    int g = b & 63, ch = b >> 6;
    int tid = threadIdx.x;
    if (tid < 128) { cnt[tid] = 0; cur[tid] = 0; }
    if (tid < SLICES_) cnt_s[tid] = bcnt[(g * SLICES_ + tid) * CHUNKS_ + ch];
    __syncthreads();
    size_t bb = (size_t)(g * CHUNKS_ + ch) * BCAP;
    const unsigned int* bl = blist + bb;
    const int TOT = SLICES_ * REG_;            // 3072
    for (int i = tid; i < TOT; i += 256) {
        int s = i / REG_, j = i - s * REG_;
        if (j < cnt_s[s]) atomicAdd(&cnt[bl[i] >> 12], 1);
    }
    __syncthreads();
    if (tid < 128) {
        int v = cnt[tid];
        int l64 = tid & 63;
#pragma unroll
        for (int o = 1; o < 64; o <<= 1) {
            int t = __shfl_up(v, o);
            if (l64 >= o) v += t;
        }
        st[tid] = v;
        if (l64 == 63) stot[tid >> 6] = v;
    }
    __syncthreads();
    if (tid >= 64 && tid < 128) st[tid] += stot[0];
    __syncthreads();
    for (int i = tid; i < TOT; i += 256) {
        int s = i / REG_, j = i - s * REG_;
        if (j < cnt_s[s]) {
            unsigned pk = bl[i];
            int dl = (int)(pk >> 12);
            int p = st[dl] - cnt[dl] + atomicAdd(&cur[dl], 1);
            sorted[p] = (unsigned short)(pk & 0xFFFu);
        }
    }
    __syncthreads();
    int n = st[127];
    for (int i = tid; i < n; i += 256) blist[bb + i] = ((unsigned int)sorted[i]) << 5;
    int lo = ch * LSTR;
    int nloc = min(LSTR, NL - lo);
    int gbase = g * NL;
    if (tid < nloc) {
        int node = gbase + lo + tid;
        int c = cnt[tid];
        int start = (int)bb + st[tid] - c;
        ninfo[node] = (start << 8) | min(c, 255);
        rsqv[tid] = rsqrtf((float)(c + 1));
    }
    __syncthreads();
    for (int idx = tid; idx < nloc * 32; idx += 256) {
        int nl = idx >> 5, f2 = idx & 31;
        int node = gbase + lo + nl;
        float sc = rsqv[nl];
        float2 v;
        if (STAGE == 1) v = ((const float2*)xf)[(size_t)node * 32 + f2];
        else            v = bf2f(xg[(size_t)node * 32 + f2]);
        xb[(size_t)node * 32 + f2] = f2bf(v.x * sc, v.y * sc);
    }
}

// ---------------- FUSED gather-aggregate + MFMA conv + score ----------------
// Wave handles 16 nodes: (a) per node, 16-lane dwordx2 gather of pre-scaled bf16 rows,
// quad-reduced via shfl_xor; row staged in LDS (stride 65 -> all LDS ops 2-way = free);
// (b) split-bf16 MFMA conv (relu(y@W+b)) + score, no __syncthreads (wave-local tile).
template<int STAGE>
__launch_bounds__(256)
__global__ void k_aggconv(const unsigned int* xb, const int* ninfo, const unsigned int* csr,
                          const float* W, const float* bias, const float* pvec,
                          float* conv, float* score) {
    const int NL = (STAGE == 1) ? N_ : K1_;
    __shared__ float yt[4][16 * 65];
    int b = blockIdx.x;
    int xcd = b & 7, r = b >> 3;
    int graph, tile;
    if (STAGE == 1) { graph = xcd * 8 + (r >> 5); tile = r & 31; }
    else            { graph = xcd * 8 + r / T2_;  tile = r % T2_; }
    int wid  = threadIdx.x >> 6;
    int lane = threadIdx.x & 63;
    int q  = lane >> 4;            // quad: which edge of a 4-group / MFMA k-slice
    int fq = lane & 15;            // 8B feature slot (features 4fq..4fq+3)
    int gbase = graph * NL;
    int gbase32 = gbase * 32;
    int rowloc0 = tile * 64 + wid * 16;        // wave's first row (graph-local)

    // ---- phase A: aggregate 16 rows into the LDS tile ----
    for (int j = 0; j < 16; j++) {
        int local = rowloc0 + j;
        bool valid = (STAGE == 1) || (local < NL);
        int node = gbase + (valid ? local : 0);
        int ni = ninfo[node];
        int cnt = ni & 255, base = ni >> 8;
        float rd = valid ? rsqrtf((float)(cnt + 1)) : 0.f;
        float f0 = 0.f, f1 = 0.f, f2 = 0.f, f3 = 0.f;
        for (int chunk = 0; chunk < cnt; chunk += 64) {
            int nch = min(64, cnt - chunk);
            int sv = 0;
            if (lane < nch) sv = gbase32 + (int)csr[base + chunk + lane];
            int i = 0;
            for (; i + 4 <= nch; i += 4) {
                int se = __shfl(sv, i + q);
                uint2 u = *(const uint2*)(xb + se + 2 * fq);
                float2 aa = bf2f(u.x), bb = bf2f(u.y);
                f0 += aa.x; f1 += aa.y; f2 += bb.x; f3 += bb.y;
            }
            if (i < nch) {
                int idx = i + q;
                int se = __shfl(sv, (idx < nch) ? idx : i);
                float m = (idx < nch) ? 1.f : 0.f;
                uint2 u = *(const uint2*)(xb + se + 2 * fq);
                float2 aa = bf2f(u.x), bb = bf2f(u.y);
                f0 += aa.x * m; f1 += aa.y * m; f2 += bb.x * m; f3 += bb.y * m;
            }
        }
        // quad reduce: all lanes end with totals for features 4fq..4fq+3
#pragma unroll
        for (int m = 16; m < 64; m <<= 1) {
            f0 += __shfl_xor(f0, m);
            f1 += __shfl_xor(f1, m);
            f2 += __shfl_xor(f2, m);
            f3 += __shfl_xor(f3, m);
        }
        uint2 us = *(const uint2*)(xb + (size_t)node * 32 + 2 * fq);   // pre-scaled self
        float2 sa = bf2f(us.x), sb = bf2f(us.y);
        f0 = (f0 + sa.x) * rd; f1 = (f1 + sa.y) * rd;
        f2 = (f2 + sb.x) * rd; f3 = (f3 + sb.y) * rd;
        // lane writes feature 4fq+q (one ds_write_b32 per row per wave)
        float wv_ = (q & 1) ? ((q & 2) ? f3 : f1) : ((q & 2) ? f2 : f0);
        yt[wid][j * 65 + 4 * fq + q] = wv_;
    }
    __builtin_amdgcn_sched_barrier(0);

    // ---- phase B: MFMA conv on the wave's own 16x64 tile ----
    int c = fq;                                // A-row / C-col index
    bf8 ah[2], al[2];
#pragma unroll
    for (int ks = 0; ks < 2; ks++) {
        bf8 h, l;
#pragma unroll
        for (int j = 0; j < 8; j++) {
            float v = yt[wid][c * 65 + ks * 32 + q * 8 + j];
            unsigned short hb = f2bf_rn(v);
            h[j] = (short)hb;
            l[j] = (short)f2bf_rn(v - __uint_as_float((unsigned)hb << 16));
        }
        ah[ks] = h; al[ks] = l;
    }
    bf8 bh[2][4], blo[2][4];
#pragma unroll
    for (int ks = 0; ks < 2; ks++)
#pragma unroll
        for (int nt = 0; nt < 4; nt++) {
            bf8 h, l;
#pragma unroll
            for (int j = 0; j < 8; j++) {
                float wv = W[(ks * 32 + q * 8 + j) * 64 + nt * 16 + c];
                unsigned short hb = f2bf_rn(wv);
                h[j] = (short)hb;
                l[j] = (short)f2bf_rn(wv - __uint_as_float((unsigned)hb << 16));
            }
            bh[ks][nt] = h; blo[ks][nt] = l;
        }
    float pp = 0.f;
#pragma unroll
    for (int i = 0; i < DIM_; i++) pp += pvec[i] * pvec[i];
    float rpn = rsqrtf(pp);
    float dot[4] = {0.f, 0.f, 0.f, 0.f};
    int growbase = gbase + rowloc0;            // global row of tile row 0
#pragma unroll
    for (int nt = 0; nt < 4; nt++) {
        f4 acc = {0.f, 0.f, 0.f, 0.f};
#pragma unroll
        for (int ks = 0; ks < 2; ks++) {
            acc = __builtin_amdgcn_mfma_f32_16x16x32_bf16(ah[ks], bh[ks][nt],  acc, 0, 0, 0);
            acc = __builtin_amdgcn_mfma_f32_16x16x32_bf16(ah[ks], blo[ks][nt], acc, 0, 0, 0);
            acc = __builtin_amdgcn_mfma_f32_16x16x32_bf16(al[ks], bh[ks][nt],  acc, 0, 0, 0);
        }
        float bcol = bias[nt * 16 + c];
        float pcol = pvec[nt * 16 + c];
#pragma unroll
        for (int reg = 0; reg < 4; reg++) {
            float v = fmaxf(acc[reg] + bcol, 0.f);
            dot[reg] += v * pcol;
            int rl = rowloc0 + q * 4 + reg;
            if (STAGE == 1 || rl < NL)
                conv[(size_t)(gbase + rl) * DIM_ + nt * 16 + c] = v;
        }
    }
#pragma unroll
    for (int m = 1; m < 16; m <<= 1) {
#pragma unroll
        for (int reg = 0; reg < 4; reg++) dot[reg] += __shfl_xor(dot[reg], m);
    }
    if (c == 0) {
#pragma unroll
        for (int reg = 0; reg < 4; reg++) {
            int rl = rowloc0 + q * 4 + reg;
            if (STAGE == 1 || rl < NL)
                score[growbase + q * 4 + reg] = tanhf(dot[reg] * rpn);
        }
    }
}

// ---------------- exact top-K: 6-pass radix select, wave-shfl suffix scan -------------------
template<int STAGE>
__launch_bounds__(256)
__global__ void k_select(const float* score, int* new_id, int* sel, float* vals) {
    const int Nin = (STAGE == 1) ? N_ : K1_;
    const int K   = (STAGE == 1) ? K1_ : K2_;
    __shared__ unsigned long long keys[N_];
    __shared__ int bins[256], wsum[4];
    __shared__ unsigned long long s_prefix;
    __shared__ int s_need, s_cnt;
    int g = blockIdx.x, tid = threadIdx.x;
    int l64 = tid & 63, wid = tid >> 6;
    const float* sg = score + (size_t)g * Nin;
    for (int i = tid; i < Nin; i += 256) {
        unsigned u = __float_as_uint(sg[i]);
        u = (u & 0x80000000u) ? ~u : (u | 0x80000000u);
        keys[i] = ((unsigned long long)u << 11) | (unsigned long long)(2047 - i);
    }
    if (tid == 0) { s_need = K; s_prefix = 0ull; s_cnt = 0; }
    __syncthreads();
    for (int shift = 40; shift >= 0; shift -= 8) {
        bins[tid] = 0;
        __syncthreads();
        unsigned long long pref = s_prefix;
        int need = s_need;
        int hi = shift + 8;
        for (int i = tid; i < Nin; i += 256) {
            unsigned long long k = keys[i];
            if ((k >> hi) == pref) atomicAdd(&bins[(int)((k >> shift) & 255)], 1);
        }
        __syncthreads();
        int mine = bins[tid];
        int v = mine;
#pragma unroll
        for (int o = 1; o < 64; o <<= 1) {
            int t = __shfl_down(v, o);
            if (l64 + o < 64) v += t;
        }
        if (l64 == 0) wsum[wid] = v;
        __syncthreads();
        for (int w = wid + 1; w < 4; w++) v += wsum[w];
        int nxt = v - mine;
        if (v >= need && nxt < need) {
            s_prefix = (pref << 8) | (unsigned long long)tid;
            s_need = need - nxt;
        }
        __syncthreads();
    }
    unsigned long long T = s_prefix;
    for (int i = tid; i < Nin; i += 256) {
        if (keys[i] >= T) {
            int r = atomicAdd(&s_cnt, 1);
            int slot = g * K + r;
            sel[slot]  = g * Nin + i;
            vals[slot] = sg[i];
            if (STAGE == 1) new_id[g * N_ + i] = slot;
        } else if (STAGE == 1) {
            new_id[g * N_ + i] = -1;
        }
    }
}

// ---------------- gated max/mean pooling; STAGE1 also materializes xg (bf16 gated rows) -----
template<int STAGE>
__launch_bounds__(256)
__global__ void k_pool(const float* conv, const int* sel, const float* vals, float* part,
                       unsigned int* xg) {
    const int K = (STAGE == 1) ? K1_ : K2_;
    int b = blockIdx.x;
    int g = b & 63, c = b >> 6;
    int wv = threadIdx.x >> 6, lane = threadIdx.x & 63;
    float mx = -3.402823466e38f, sm = 0.f;
    for (int r = c * 4 + wv; r < K; r += PB_ * 4) {
        int slot = g * K + r;
        int row  = sel[slot];
        float val = vals[slot];
        float v = conv[(size_t)row * DIM_ + lane] * val;
        mx = fmaxf(mx, v);
        sm += v;
        if (STAGE == 1) {
            unsigned pk = f2bf(v, __shfl_xor(v, 1));
            if (!(lane & 1)) xg[(size_t)slot * 32 + (lane >> 1)] = pk;
        }
    }
    __shared__ float rmx[4][64], rsm[4][64];
    rmx[wv][lane] = mx; rsm[wv][lane] = sm;
    __syncthreads();
    if (wv == 0) {
        mx = fmaxf(fmaxf(rmx[0][lane], rmx[1][lane]), fmaxf(rmx[2][lane], rmx[3][lane]));
        sm = rsm[0][lane] + rsm[1][lane] + rsm[2][lane] + rsm[3][lane];
        part[((size_t)(g * PB_ + c) * 2 + 0) * 64 + lane] = mx;
        part[((size_t)(g * PB_ + c) * 2 + 1) * 64 + lane] = sm;
    }
}

// ---------------- MLP head (fused partial-combine for both stages) ----------------
__launch_bounds__(64)
__global__ void k_head(const float* part1, const float* part2,
                       const float* l1w, const float* l1b,
                       const float* l2w, const float* l2b, float* out) {
    __shared__ float h[128];
    __shared__ float h1[64];
    int g = blockIdx.x, t = threadIdx.x;
    float mx1 = -3.402823466e38f, sm1 = 0.f, mx2 = -3.402823466e38f, sm2 = 0.f;
#pragma unroll
    for (int c = 0; c < PB_; c++) {
        mx1 = fmaxf(mx1, part1[((size_t)(g * PB_ + c) * 2 + 0) * 64 + t]);
        sm1 += part1[((size_t)(g * PB_ + c) * 2 + 1) * 64 + t];
        mx2 = fmaxf(mx2, part2[((size_t)(g * PB_ + c) * 2 + 0) * 64 + t]);
        sm2 += part2[((size_t)(g * PB_ + c) * 2 + 1) * 64 + t];
    }
    h[t]      = mx1 + mx2;
    h[t + 64] = sm1 / (float)K1_ + sm2 / (float)K2_;
    __syncthreads();
    float acc = l1b[t];
#pragma unroll 8
    for (int i = 0; i < 128; i++) acc += h[i] * l1w[i * 64 + t];
    h1[t] = fmaxf(acc, 0.0f);
    __syncthreads();
    if (t < NCLS) {
        float o = l2b[t];
#pragma unroll
        for (int i = 0; i < 64; i++) o += h1[i] * l2w[i * NCLS + t];
        out[g * NCLS + t] = o;
    }
}

extern "C" void kernel_launch(void* const* d_in, const int* in_sizes, int n_in,
                              void* d_out, int out_size, void* d_ws, size_t ws_size,
                              hipStream_t stream) {
    const float* x   = (const float*)d_in[0];
    const int*   ei  = (const int*)d_in[1];
    const int*   src = ei;
    const int*   dst = ei + ETOT;
    const float* W1  = (const float*)d_in[3];
    const float* b1  = (const float*)d_in[4];
    const float* p1  = (const float*)d_in[5];
    const float* W2  = (const float*)d_in[6];
    const float* b2  = (const float*)d_in[7];
    const float* p2  = (const float*)d_in[8];
    const float* l1w = (const float*)d_in[9];
    const float* l1b = (const float*)d_in[10];
    const float* l2w = (const float*)d_in[11];
    const float* l2b = (const float*)d_in[12];
    (void)in_sizes; (void)n_in; (void)out_size; (void)ws_size;

    // workspace layout (~93 MB); xg aliases bufB (dead until aggconv2 writes it)
    char* ws = (char*)d_ws;
    size_t off = 0;
    auto alloc = [&](size_t bytes) -> void* {
        void* p = ws + off;
        off = (off + bytes + 255) & ~(size_t)255;
        return p;
    };
    float*        bufA  = (float*)       alloc((size_t)NTOT  * DIM_ * 4);  // conv1
    float*        bufB  = (float*)       alloc((size_t)N2TOT * DIM_ * 4);  // xg, then conv2
    unsigned int* blist = (unsigned int*)alloc((size_t)B_ * CHUNKS_ * BCAP * 4); // buckets -> csr
    unsigned int* xb    = (unsigned int*)alloc((size_t)NTOT * 32 * 4);     // bf16 prescaled rows
    int*          bcnt  = (int*)         alloc((size_t)B_ * SLICES_ * CHUNKS_ * 4);
    int*          ninfo = (int*)         alloc((size_t)NTOT * 4);
    float*        score = (float*)       alloc((size_t)NTOT * 4);
    int*          newid = (int*)         alloc((size_t)NTOT * 4);
    int*          sel1  = (int*)         alloc((size_t)N2TOT * 4);
    float*        vals1 = (float*)       alloc((size_t)N2TOT * 4);
    int*          sel2  = (int*)         alloc((size_t)B_ * K2_ * 4);
    float*        vals2 = (float*)       alloc((size_t)B_ * K2_ * 4);
    float*        part1 = (float*)       alloc((size_t)B_ * PB_ * 128 * 4);
    float*        part2 = (float*)       alloc((size_t)B_ * PB_ * 128 * 4);
    unsigned int* xg    = (unsigned int*)bufB;   // alias: gated bf16 rows, consumed by sort2

    // ---- stage 1 ----
    k_bucket<1><<<B_ * SLICES_, 256, 0, stream>>>(src, dst, nullptr, bcnt, blist);
    k_sort<1><<<B_ * CHUNKS_, 256, 0, stream>>>(bcnt, blist, x, nullptr, xb, ninfo);
    k_aggconv<1><<<NTOT / 64, 256, 0, stream>>>(xb, ninfo, blist, W1, b1, p1, bufA, score);
    k_select<1><<<B_, 256, 0, stream>>>(score, newid, sel1, vals1);
    k_pool<1><<<B_ * PB_, 256, 0, stream>>>(bufA, sel1, vals1, part1, xg);

    // ---- stage 2 ----
    k_bucket<2><<<B_ * SLICES_, 256, 0, stream>>>(src, dst, newid, bcnt, blist);
    k_sort<2><<<B_ * CHUNKS_, 256, 0, stream>>>(bcnt, blist, nullptr, xg, xb, ninfo);
    k_aggconv<2><<<B_ * T2_, 256, 0, stream>>>(xb, ninfo, blist, W2, b2, p2, bufB, score);
    k_select<2><<<B_, 256, 0, stream>>>(score, nullptr, sel2, vals2);
    k_pool<2><<<B_ * PB_, 256, 0, stream>>>(bufB, sel2, vals2, part2, nullptr);

    // ---- head (fused combine) ----
    k_head<<<B_, 64, 0, stream>>>(part1, part2, l1w, l1b, l2w, l2b, (float*)d_out);
}

// Round 16
// 351.320 us; speedup vs baseline: 1.0925x; 1.0925x over previous
//
#include <hip/hip_runtime.h>
#include <hip/hip_bf16.h>
#include <cstdint>
#include <cstddef>

#define B_    64
#define N_    2048
#define E_    32768            // edges per graph
#define DIM_  64
#define K1_   1639
#define K2_   1312
#define NTOT  (B_ * N_)        // 131072
#define ETOT  (B_ * E_)        // 2097152
#define N2TOT (B_ * K1_)       // 104896
#define NCLS  6
#define PB_   8                // pooling blocks per graph
#define CHUNKS_ 16             // dst-chunks per graph
#define SLICES_ 16             // edge slices per graph in k_bucket
#define BCAP  3072             // bucket capacity (= SLICES_*REG_)
#define REG_  192              // per-slice region (mean 128, sd ~11 -> +5.8 sigma)

typedef short bf8 __attribute__((ext_vector_type(8)));
typedef float f4  __attribute__((ext_vector_type(4)));

static __device__ __forceinline__ float2 bf2f(unsigned u) {
    float2 r;
    r.x = __uint_as_float(u << 16);
    r.y = __uint_as_float(u & 0xFFFF0000u);
    return r;
}
static __device__ __forceinline__ unsigned f2bf(float a, float b) {
    __hip_bfloat162 h = __float22bfloat162_rn(make_float2(a, b));
    unsigned u;
    __builtin_memcpy(&u, &h, 4);
    return u;
}
static __device__ __forceinline__ unsigned short f2bf_rn(float v) {
    unsigned u = __float_as_uint(v);
    return (unsigned short)((u + 0x7FFFu + ((u >> 16) & 1u)) >> 16);
}

// ---------------- bucket edges by (graph, dst-chunk) into slice-owned regions --------------
template<int STAGE>
__launch_bounds__(256)
__global__ void k_bucket(const int* src, const int* dst, const int* remap,
                         int* bcnt, unsigned int* blist) {
    const int LSTR = (STAGE == 1) ? 128 : 103;
    __shared__ unsigned int lb[CHUNKS_][REG_];
    __shared__ int lc[CHUNKS_];
    __shared__ int rm[N_];                     // stage2 only
    int b = blockIdx.x;
    int g = b & 63, slice = b >> 6;
    int tid = threadIdx.x;
    if (tid < CHUNKS_) lc[tid] = 0;
    if (STAGE == 2)
        for (int i = tid; i < N_; i += 256) rm[i] = remap[g * N_ + i];
    __syncthreads();
    const int ESL = E_ / SLICES_;              // 2048
    const int* sp = src + (size_t)g * E_ + slice * ESL;
    const int* dp = dst + (size_t)g * E_ + slice * ESL;
    int gbase = g * ((STAGE == 1) ? N_ : K1_);
    for (int e = tid * 4; e < ESL; e += 1024) {
        int4 ss = *(const int4*)&sp[e];
        int4 dd = *(const int4*)&dp[e];
#pragma unroll
        for (int t = 0; t < 4; t++) {
            int s = (&ss.x)[t], d = (&dd.x)[t];
            if (STAGE == 2) {
                s = rm[s & (N_ - 1)]; d = rm[d & (N_ - 1)];
                if ((s | d) < 0) continue;     // edge touches a dropped node
                s -= gbase; d -= gbase;
            } else {
                s &= (N_ - 1); d &= (N_ - 1);
            }
            int ch = d / LSTR;
            int dl = d - ch * LSTR;
            int p = atomicAdd(&lc[ch], 1);
            if (p < REG_) lb[ch][p] = ((unsigned)dl << 12) | (unsigned)s;
        }
    }
    __syncthreads();
    for (int ch = 0; ch < CHUNKS_; ch++) {
        int n = min(lc[ch], REG_);
        unsigned int* out = blist + (size_t)(g * CHUNKS_ + ch) * BCAP + slice * REG_;
        for (int i = tid; i < n; i += 256) out[i] = lb[ch][i];
    }
    if (tid < CHUNKS_) bcnt[(g * SLICES_ + slice) * CHUNKS_ + tid] = min(lc[tid], REG_);
}

// ---------------- counting-sort -> in-place compact CSR (pre-shifted) + ninfo + prescale ----
template<int STAGE>
__launch_bounds__(256)
__global__ void k_sort(const int* bcnt, unsigned int* blist,
                       const float* xf, const unsigned int* xg,
                       unsigned int* xb, int* ninfo) {
    const int NL   = (STAGE == 1) ? N_ : K1_;
    const int LSTR = (STAGE == 1) ? 128 : 103;
    __shared__ int cnt[128], st[128], cur[128], cnt_s[SLICES_], stot[2];
    __shared__ float rsqv[128];
    __shared__ unsigned short sorted[BCAP];
    int b = blockIdx.x;
    int g = b & 63, ch = b >> 6;
    int tid = threadIdx.x;
    if (tid < 128) { cnt[tid] = 0; cur[tid] = 0; }
    if (tid < SLICES_) cnt_s[tid] = bcnt[(g * SLICES_ + tid) * CHUNKS_ + ch];
    __syncthreads();
    size_t bb = (size_t)(g * CHUNKS_ + ch) * BCAP;
    const unsigned int* bl = blist + bb;
    const int TOT = SLICES_ * REG_;            // 3072
    for (int i = tid; i < TOT; i += 256) {
        int s = i / REG_, j = i - s * REG_;
        if (j < cnt_s[s]) atomicAdd(&cnt[bl[i] >> 12], 1);
    }
    __syncthreads();
    if (tid < 128) {
        int v = cnt[tid];
        int l64 = tid & 63;
#pragma unroll
        for (int o = 1; o < 64; o <<= 1) {
            int t = __shfl_up(v, o);
            if (l64 >= o) v += t;
        }
        st[tid] = v;
        if (l64 == 63) stot[tid >> 6] = v;
    }
    __syncthreads();
    if (tid >= 64 && tid < 128) st[tid] += stot[0];
    __syncthreads();
    for (int i = tid; i < TOT; i += 256) {
        int s = i / REG_, j = i - s * REG_;
        if (j < cnt_s[s]) {
            unsigned pk = bl[i];
            int dl = (int)(pk >> 12);
            int p = st[dl] - cnt[dl] + atomicAdd(&cur[dl], 1);
            sorted[p] = (unsigned short)(pk & 0xFFFu);
        }
    }
    __syncthreads();
    int n = st[127];
    for (int i = tid; i < n; i += 256) blist[bb + i] = ((unsigned int)sorted[i]) << 5;
    int lo = ch * LSTR;
    int nloc = min(LSTR, NL - lo);
    int gbase = g * NL;
    if (tid < nloc) {
        int node = gbase + lo + tid;
        int c = cnt[tid];
        int start = (int)bb + st[tid] - c;
        ninfo[node] = (start << 8) | min(c, 255);
        rsqv[tid] = rsqrtf((float)(c + 1));
    }
    __syncthreads();
    for (int idx = tid; idx < nloc * 32; idx += 256) {
        int nl = idx >> 5, f2 = idx & 31;
        int node = gbase + lo + nl;
        float sc = rsqv[nl];
        float2 v;
        if (STAGE == 1) v = ((const float2*)xf)[(size_t)node * 32 + f2];
        else            v = bf2f(xg[(size_t)node * 32 + f2]);
        xb[(size_t)node * 32 + f2] = f2bf(v.x * sc, v.y * sc);
    }
}

// ---------------- gather-aggregate over pre-scaled bf16 rows ----------------
// Wave per node. 16 lanes per edge (uint2 = 4 features/lane), 4 edge-groups, 4-deep unroll
// -> 4 independent 8B loads in flight per lane; xor-shuffle combine; float4 store by 16 lanes.
template<bool GATE>
__launch_bounds__(256)
__global__ void k_agg(const unsigned int* xb, const int* ninfo, const unsigned int* csr,
                      float* y) {
    int b = blockIdx.x;
    int xcd = b & 7, r = b >> 3;
    int graph, local;
    if (GATE) {
        graph = xcd * 8 + r / 410;            // ceil(1639/4)=410 blocks/graph
        local = (r % 410) * 4 + (threadIdx.x >> 6);
        if (local >= K1_) return;
    } else {
        graph = xcd * 8 + (r >> 9);           // 512 blocks/graph
        local = (r & 511) * 4 + (threadIdx.x >> 6);
    }
    const int NL = GATE ? K1_ : N_;
    int node = graph * NL + local;
    int lane = threadIdx.x & 63;
    int grp = lane >> 4;                       // edge-group 0..3
    int fq  = lane & 15;                       // feature quad: features 4fq..4fq+3
    int ni = ninfo[node];
    int cnt = ni & 255, base = ni >> 8;
    float rd = rsqrtf((float)(cnt + 1));
    float f0 = 0.f, f1 = 0.f, f2_ = 0.f, f3 = 0.f;
    int gbase32 = graph * NL * 32;
    for (int chunk = 0; chunk < cnt; chunk += 64) {
        int nch = min(64, cnt - chunk);
        int sv = 0;
        if (lane < nch) sv = gbase32 + (int)csr[base + chunk + lane];   // element offset
        int i = 0;
        for (; i + 16 <= nch; i += 16) {       // 16 edges, 4 loads in flight per lane
            int s0 = __shfl(sv, i + grp),      s1 = __shfl(sv, i + 4 + grp),
                s2 = __shfl(sv, i + 8 + grp),  s3 = __shfl(sv, i + 12 + grp);
            uint2 u0 = *(const uint2*)(xb + s0 + 2 * fq);
            uint2 u1 = *(const uint2*)(xb + s1 + 2 * fq);
            uint2 u2 = *(const uint2*)(xb + s2 + 2 * fq);
            uint2 u3 = *(const uint2*)(xb + s3 + 2 * fq);
            float2 a0 = bf2f(u0.x), b0 = bf2f(u0.y);
            float2 a1 = bf2f(u1.x), b1 = bf2f(u1.y);
            float2 a2 = bf2f(u2.x), b2 = bf2f(u2.y);
            float2 a3 = bf2f(u3.x), b3 = bf2f(u3.y);
            f0 += a0.x + a1.x + a2.x + a3.x;
            f1 += a0.y + a1.y + a2.y + a3.y;
            f2_ += b0.x + b1.x + b2.x + b3.x;
            f3 += b0.y + b1.y + b2.y + b3.y;
        }
        for (; i + 4 <= nch; i += 4) {
            int s0 = __shfl(sv, i + grp);
            uint2 u0 = *(const uint2*)(xb + s0 + 2 * fq);
            float2 a0 = bf2f(u0.x), b0 = bf2f(u0.y);
            f0 += a0.x; f1 += a0.y; f2_ += b0.x; f3 += b0.y;
        }
        if (i < nch) {                         // partial group of 1..3 edges
            int idx = i + grp;
            int s0 = __shfl(sv, (idx < nch) ? idx : i);
            float m = (idx < nch) ? 1.f : 0.f;
            uint2 u0 = *(const uint2*)(xb + s0 + 2 * fq);
            float2 a0 = bf2f(u0.x), b0 = bf2f(u0.y);
            f0 += a0.x * m; f1 += a0.y * m; f2_ += b0.x * m; f3 += b0.y * m;
        }
    }
#pragma unroll
    for (int m = 16; m < 64; m <<= 1) {        // combine the 4 edge-groups
        f0 += __shfl_xor(f0, m);
        f1 += __shfl_xor(f1, m);
        f2_ += __shfl_xor(f2_, m);
        f3 += __shfl_xor(f3, m);
    }
    uint2 us = *(const uint2*)(xb + (size_t)node * 32 + 2 * fq);       // pre-scaled self
    float2 sa = bf2f(us.x), sb = bf2f(us.y);
    if (grp == 0) {
        float4 o;
        o.x = (f0 + sa.x) * rd;
        o.y = (f1 + sa.y) * rd;
        o.z = (f2_ + sb.x) * rd;
        o.w = (f3 + sb.y) * rd;
        *(float4*)(y + (size_t)node * DIM_ + fq * 4) = o;
    }
}

// ---------------- MFMA conv: conv = relu(y @ W + b), score = tanh(conv.p/||p||) ------------
__launch_bounds__(256)
__global__ void k_convrow(float* y, const float* W, const float* bias, const float* pvec,
                          float* score, int rows) {
    int wid  = threadIdx.x >> 6;
    int lane = threadIdx.x & 63;
    int rowbase = blockIdx.x * 64 + wid * 16;
    int q = lane >> 4, c = lane & 15;
    bf8 bh[2][4], blo[2][4];
#pragma unroll
    for (int ks = 0; ks < 2; ks++)
#pragma unroll
        for (int nt = 0; nt < 4; nt++) {
            bf8 h, l;
#pragma unroll
            for (int j = 0; j < 8; j++) {
                float wv = W[(ks * 32 + q * 8 + j) * 64 + nt * 16 + c];
                unsigned short hb = f2bf_rn(wv);
                h[j] = (short)hb;
                l[j] = (short)f2bf_rn(wv - __uint_as_float((unsigned)hb << 16));
            }
            bh[ks][nt] = h; blo[ks][nt] = l;
        }
    const float* yr = y + (size_t)(rowbase + c) * DIM_ + q * 8;
    bf8 ah[2], al[2];
#pragma unroll
    for (int ks = 0; ks < 2; ks++) {
        float4 v0 = *(const float4*)(yr + ks * 32);
        float4 v1 = *(const float4*)(yr + ks * 32 + 4);
        float vv[8] = {v0.x, v0.y, v0.z, v0.w, v1.x, v1.y, v1.z, v1.w};
        bf8 h, l;
#pragma unroll
        for (int j = 0; j < 8; j++) {
            unsigned short hb = f2bf_rn(vv[j]);
            h[j] = (short)hb;
            l[j] = (short)f2bf_rn(vv[j] - __uint_as_float((unsigned)hb << 16));
        }
        ah[ks] = h; al[ks] = l;
    }
    float pp = 0.f;
#pragma unroll
    for (int i = 0; i < DIM_; i++) pp += pvec[i] * pvec[i];
    float rpn = rsqrtf(pp);
    float dot[4] = {0.f, 0.f, 0.f, 0.f};
#pragma unroll
    for (int nt = 0; nt < 4; nt++) {
        f4 acc = {0.f, 0.f, 0.f, 0.f};
#pragma unroll
        for (int ks = 0; ks < 2; ks++) {
            acc = __builtin_amdgcn_mfma_f32_16x16x32_bf16(ah[ks], bh[ks][nt],  acc, 0, 0, 0);
            acc = __builtin_amdgcn_mfma_f32_16x16x32_bf16(ah[ks], blo[ks][nt], acc, 0, 0, 0);
            acc = __builtin_amdgcn_mfma_f32_16x16x32_bf16(al[ks], bh[ks][nt],  acc, 0, 0, 0);
        }
        float bcol = bias[nt * 16 + c];
        float pcol = pvec[nt * 16 + c];
        float st[4];
#pragma unroll
        for (int reg = 0; reg < 4; reg++) {
            float v = fmaxf(acc[reg] + bcol, 0.f);
            st[reg] = v;
            dot[reg] += v * pcol;
        }
#pragma unroll
        for (int reg = 0; reg < 4; reg++)
            y[(size_t)(rowbase + q * 4 + reg) * DIM_ + nt * 16 + c] = st[reg];
    }
#pragma unroll
    for (int m = 1; m < 16; m <<= 1) {
#pragma unroll
        for (int reg = 0; reg < 4; reg++) dot[reg] += __shfl_xor(dot[reg], m);
    }
    if (c == 0) {
#pragma unroll
        for (int reg = 0; reg < 4; reg++)
            score[rowbase + q * 4 + reg] = tanhf(dot[reg] * rpn);
    }
    (void)rows;
}

// ---------------- exact top-K: 6-pass radix select, wave-shfl suffix scan -------------------
template<int STAGE>
__launch_bounds__(256)
__global__ void k_select(const float* score, int* new_id, int* sel, float* vals) {
    const int Nin = (STAGE == 1) ? N_ : K1_;
    const int K   = (STAGE == 1) ? K1_ : K2_;
    __shared__ unsigned long long keys[N_];
    __shared__ int bins[256], wsum[4];
    __shared__ unsigned long long s_prefix;
    __shared__ int s_need, s_cnt;
    int g = blockIdx.x, tid = threadIdx.x;
    int l64 = tid & 63, wid = tid >> 6;
    const float* sg = score + (size_t)g * Nin;
    for (int i = tid; i < Nin; i += 256) {
        unsigned u = __float_as_uint(sg[i]);
        u = (u & 0x80000000u) ? ~u : (u | 0x80000000u);
        keys[i] = ((unsigned long long)u << 11) | (unsigned long long)(2047 - i);
    }
    if (tid == 0) { s_need = K; s_prefix = 0ull; s_cnt = 0; }
    __syncthreads();
    for (int shift = 40; shift >= 0; shift -= 8) {
        bins[tid] = 0;
        __syncthreads();
        unsigned long long pref = s_prefix;
        int need = s_need;
        int hi = shift + 8;
        for (int i = tid; i < Nin; i += 256) {
            unsigned long long k = keys[i];
            if ((k >> hi) == pref) atomicAdd(&bins[(int)((k >> shift) & 255)], 1);
        }
        __syncthreads();
        int mine = bins[tid];
        int v = mine;
#pragma unroll
        for (int o = 1; o < 64; o <<= 1) {
            int t = __shfl_down(v, o);
            if (l64 + o < 64) v += t;
        }
        if (l64 == 0) wsum[wid] = v;
        __syncthreads();
        for (int w = wid + 1; w < 4; w++) v += wsum[w];
        int nxt = v - mine;
        if (v >= need && nxt < need) {
            s_prefix = (pref << 8) | (unsigned long long)tid;
            s_need = need - nxt;
        }
        __syncthreads();
    }
    unsigned long long T = s_prefix;
    for (int i = tid; i < Nin; i += 256) {
        if (keys[i] >= T) {
            int r = atomicAdd(&s_cnt, 1);
            int slot = g * K + r;
            sel[slot]  = g * Nin + i;
            vals[slot] = sg[i];
            if (STAGE == 1) new_id[g * N_ + i] = slot;
        } else if (STAGE == 1) {
            new_id[g * N_ + i] = -1;
        }
    }
}

// ---------------- gated max/mean pooling; STAGE1 also materializes xg (bf16 gated rows) -----
template<int STAGE>
__launch_bounds__(256)
__global__ void k_pool(const float* conv, const int* sel, const float* vals, float* part,
                       unsigned int* xg) {
    const int K = (STAGE == 1) ? K1_ : K2_;
    int b = blockIdx.x;
    int g = b & 63, c = b >> 6;
    int wv = threadIdx.x >> 6, lane = threadIdx.x & 63;
    float mx = -3.402823466e38f, sm = 0.f;
    for (int r = c * 4 + wv; r < K; r += PB_ * 4) {
        int slot = g * K + r;
        int row  = sel[slot];
        float val = vals[slot];
        float v = conv[(size_t)row * DIM_ + lane] * val;
        mx = fmaxf(mx, v);
        sm += v;
        if (STAGE == 1) {
            unsigned pk = f2bf(v, __shfl_xor(v, 1));
            if (!(lane & 1)) xg[(size_t)slot * 32 + (lane >> 1)] = pk;
        }
    }
    __shared__ float rmx[4][64], rsm[4][64];
    rmx[wv][lane] = mx; rsm[wv][lane] = sm;
    __syncthreads();
    if (wv == 0) {
        mx = fmaxf(fmaxf(rmx[0][lane], rmx[1][lane]), fmaxf(rmx[2][lane], rmx[3][lane]));
        sm = rsm[0][lane] + rsm[1][lane] + rsm[2][lane] + rsm[3][lane];
        part[((size_t)(g * PB_ + c) * 2 + 0) * 64 + lane] = mx;
        part[((size_t)(g * PB_ + c) * 2 + 1) * 64 + lane] = sm;
    }
}

// ---------------- MLP head (fused partial-combine for both stages) ----------------
__launch_bounds__(64)
__global__ void k_head(const float* part1, const float* part2,
                       const float* l1w, const float* l1b,
                       const float* l2w, const float* l2b, float* out) {
    __shared__ float h[128];
    __shared__ float h1[64];
    int g = blockIdx.x, t = threadIdx.x;
    float mx1 = -3.402823466e38f, sm1 = 0.f, mx2 = -3.402823466e38f, sm2 = 0.f;
#pragma unroll
    for (int c = 0; c < PB_; c++) {
        mx1 = fmaxf(mx1, part1[((size_t)(g * PB_ + c) * 2 + 0) * 64 + t]);
        sm1 += part1[((size_t)(g * PB_ + c) * 2 + 1) * 64 + t];
        mx2 = fmaxf(mx2, part2[((size_t)(g * PB_ + c) * 2 + 0) * 64 + t]);
        sm2 += part2[((size_t)(g * PB_ + c) * 2 + 1) * 64 + t];
    }
    h[t]      = mx1 + mx2;
    h[t + 64] = sm1 / (float)K1_ + sm2 / (float)K2_;
    __syncthreads();
    float acc = l1b[t];
#pragma unroll 8
    for (int i = 0; i < 128; i++) acc += h[i] * l1w[i * 64 + t];
    h1[t] = fmaxf(acc, 0.0f);
    __syncthreads();
    if (t < NCLS) {
        float o = l2b[t];
#pragma unroll
        for (int i = 0; i < 64; i++) o += h1[i] * l2w[i * NCLS + t];
        out[g * NCLS + t] = o;
    }
}

extern "C" void kernel_launch(void* const* d_in, const int* in_sizes, int n_in,
                              void* d_out, int out_size, void* d_ws, size_t ws_size,
                              hipStream_t stream) {
    const float* x   = (const float*)d_in[0];
    const int*   ei  = (const int*)d_in[1];
    const int*   src = ei;
    const int*   dst = ei + ETOT;
    const float* W1  = (const float*)d_in[3];
    const float* b1  = (const float*)d_in[4];
    const float* p1  = (const float*)d_in[5];
    const float* W2  = (const float*)d_in[6];
    const float* b2  = (const float*)d_in[7];
    const float* p2  = (const float*)d_in[8];
    const float* l1w = (const float*)d_in[9];
    const float* l1b = (const float*)d_in[10];
    const float* l2w = (const float*)d_in[11];
    const float* l2b = (const float*)d_in[12];
    (void)in_sizes; (void)n_in; (void)out_size; (void)ws_size;

    // workspace layout (~93 MB); xg aliases bufB (dead until agg2 writes it)
    char* ws = (char*)d_ws;
    size_t off = 0;
    auto alloc = [&](size_t bytes) -> void* {
        void* p = ws + off;
        off = (off + bytes + 255) & ~(size_t)255;
        return p;
    };
    float*        bufA  = (float*)       alloc((size_t)NTOT  * DIM_ * 4);  // y1 -> conv1
    float*        bufB  = (float*)       alloc((size_t)N2TOT * DIM_ * 4);  // xg, then y2 -> conv2
    unsigned int* blist = (unsigned int*)alloc((size_t)B_ * CHUNKS_ * BCAP * 4); // buckets -> csr
    unsigned int* xb    = (unsigned int*)alloc((size_t)NTOT * 32 * 4);     // bf16 prescaled rows
    int*          bcnt  = (int*)         alloc((size_t)B_ * SLICES_ * CHUNKS_ * 4);
    int*          ninfo = (int*)         alloc((size_t)NTOT * 4);
    float*        score = (float*)       alloc((size_t)NTOT * 4);
    int*          newid = (int*)         alloc((size_t)NTOT * 4);
    int*          sel1  = (int*)         alloc((size_t)N2TOT * 4);
    float*        vals1 = (float*)       alloc((size_t)N2TOT * 4);
    int*          sel2  = (int*)         alloc((size_t)B_ * K2_ * 4);
    float*        vals2 = (float*)       alloc((size_t)B_ * K2_ * 4);
    float*        part1 = (float*)       alloc((size_t)B_ * PB_ * 128 * 4);
    float*        part2 = (float*)       alloc((size_t)B_ * PB_ * 128 * 4);
    unsigned int* xg    = (unsigned int*)bufB;   // alias: gated bf16 rows, consumed by sort2

    // ---- stage 1 ----
    k_bucket<1><<<B_ * SLICES_, 256, 0, stream>>>(src, dst, nullptr, bcnt, blist);
    k_sort<1><<<B_ * CHUNKS_, 256, 0, stream>>>(bcnt, blist, x, nullptr, xb, ninfo);
    k_agg<false><<<NTOT / 4, 256, 0, stream>>>(xb, ninfo, blist, bufA);
    k_convrow<<<NTOT / 64, 256, 0, stream>>>(bufA, W1, b1, p1, score, NTOT);
    k_select<1><<<B_, 256, 0, stream>>>(score, newid, sel1, vals1);
    k_pool<1><<<B_ * PB_, 256, 0, stream>>>(bufA, sel1, vals1, part1, xg);

    // ---- stage 2 ----
    k_bucket<2><<<B_ * SLICES_, 256, 0, stream>>>(src, dst, newid, bcnt, blist);
    k_sort<2><<<B_ * CHUNKS_, 256, 0, stream>>>(bcnt, blist, nullptr, xg, xb, ninfo);
    k_agg<true><<<410 * B_, 256, 0, stream>>>(xb, ninfo, blist, bufB);
    k_convrow<<<N2TOT / 64, 256, 0, stream>>>(bufB, W2, b2, p2, score, N2TOT);
    k_select<2><<<B_, 256, 0, stream>>>(score, nullptr, sel2, vals2);
    k_pool<2><<<B_ * PB_, 256, 0, stream>>>(bufB, sel2, vals2, part2, nullptr);

    // ---- head (fused combine) ----
    k_head<<<B_, 64, 0, stream>>>(part1, part2, l1w, l1b, l2w, l2b, (float*)d_out);
}

// Round 17
// 349.623 us; speedup vs baseline: 1.0978x; 1.0049x over previous
//
#include <hip/hip_runtime.h>
#include <hip/hip_bf16.h>
#include <cstdint>
#include <cstddef>

#define B_    64
#define N_    2048
#define E_    32768            // edges per graph
#define DIM_  64
#define K1_   1639
#define K2_   1312
#define NTOT  (B_ * N_)        // 131072
#define ETOT  (B_ * E_)        // 2097152
#define N2TOT (B_ * K1_)       // 104896
#define NCLS  6
#define CHUNKS_ 16             // dst-chunks per graph
#define SLICES_ 16             // edge slices per graph in k_bucket
#define BCAP  3072             // bucket capacity (= SLICES_*REG_)
#define REG_  192              // per-slice region (mean 128, sd ~11 -> +5.8 sigma)

typedef short bf8 __attribute__((ext_vector_type(8)));
typedef float f4  __attribute__((ext_vector_type(4)));

static __device__ __forceinline__ float2 bf2f(unsigned u) {
    float2 r;
    r.x = __uint_as_float(u << 16);
    r.y = __uint_as_float(u & 0xFFFF0000u);
    return r;
}
static __device__ __forceinline__ unsigned f2bf(float a, float b) {
    __hip_bfloat162 h = __float22bfloat162_rn(make_float2(a, b));
    unsigned u;
    __builtin_memcpy(&u, &h, 4);
    return u;
}
static __device__ __forceinline__ unsigned short f2bf_rn(float v) {
    unsigned u = __float_as_uint(v);
    return (unsigned short)((u + 0x7FFFu + ((u >> 16) & 1u)) >> 16);
}

// ---------------- bucket edges by (graph, dst-chunk) into slice-owned regions --------------
template<int STAGE>
__launch_bounds__(256)
__global__ void k_bucket(const int* src, const int* dst, const int* remap,
                         int* bcnt, unsigned int* blist) {
    const int LSTR = (STAGE == 1) ? 128 : 103;
    __shared__ unsigned int lb[CHUNKS_][REG_];
    __shared__ int lc[CHUNKS_];
    __shared__ int rm[N_];                     // stage2 only
    int b = blockIdx.x;
    int g = b & 63, slice = b >> 6;
    int tid = threadIdx.x;
    if (tid < CHUNKS_) lc[tid] = 0;
    if (STAGE == 2)
        for (int i = tid; i < N_; i += 256) rm[i] = remap[g * N_ + i];
    __syncthreads();
    const int ESL = E_ / SLICES_;              // 2048
    const int* sp = src + (size_t)g * E_ + slice * ESL;
    const int* dp = dst + (size_t)g * E_ + slice * ESL;
    int gbase = g * ((STAGE == 1) ? N_ : K1_);
    for (int e = tid * 4; e < ESL; e += 1024) {
        int4 ss = *(const int4*)&sp[e];
        int4 dd = *(const int4*)&dp[e];
#pragma unroll
        for (int t = 0; t < 4; t++) {
            int s = (&ss.x)[t], d = (&dd.x)[t];
            if (STAGE == 2) {
                s = rm[s & (N_ - 1)]; d = rm[d & (N_ - 1)];
                if ((s | d) < 0) continue;     // edge touches a dropped node
                s -= gbase; d -= gbase;
            } else {
                s &= (N_ - 1); d &= (N_ - 1);
            }
            int ch = d / LSTR;
            int dl = d - ch * LSTR;
            int p = atomicAdd(&lc[ch], 1);
            if (p < REG_) lb[ch][p] = ((unsigned)dl << 12) | (unsigned)s;
        }
    }
    __syncthreads();
    for (int ch = 0; ch < CHUNKS_; ch++) {
        int n = min(lc[ch], REG_);
        unsigned int* out = blist + (size_t)(g * CHUNKS_ + ch) * BCAP + slice * REG_;
        for (int i = tid; i < n; i += 256) out[i] = lb[ch][i];
    }
    if (tid < CHUNKS_) bcnt[(g * SLICES_ + slice) * CHUNKS_ + tid] = min(lc[tid], REG_);
}

// ---------------- counting-sort -> in-place compact CSR (pre-shifted) + ninfo + prescale ----
template<int STAGE>
__launch_bounds__(256)
__global__ void k_sort(const int* bcnt, unsigned int* blist,
                       const float* xf, const unsigned int* xg,
                       unsigned int* xb, int* ninfo) {
    const int NL   = (STAGE == 1) ? N_ : K1_;
    const int LSTR = (STAGE == 1) ? 128 : 103;
    __shared__ int cnt[128], st[128], cur[128], cnt_s[SLICES_], stot[2];
    __shared__ float rsqv[128];
    __shared__ unsigned short sorted[BCAP];
    int b = blockIdx.x;
    int g = b & 63, ch = b >> 6;
    int tid = threadIdx.x;
    if (tid < 128) { cnt[tid] = 0; cur[tid] = 0; }
    if (tid < SLICES_) cnt_s[tid] = bcnt[(g * SLICES_ + tid) * CHUNKS_ + ch];
    __syncthreads();
    size_t bb = (size_t)(g * CHUNKS_ + ch) * BCAP;
    const unsigned int* bl = blist + bb;
    const int TOT = SLICES_ * REG_;            // 3072
    for (int i = tid; i < TOT; i += 256) {
        int s = i / REG_, j = i - s * REG_;
        if (j < cnt_s[s]) atomicAdd(&cnt[bl[i] >> 12], 1);
    }
    __syncthreads();
    if (tid < 128) {
        int v = cnt[tid];
        int l64 = tid & 63;
#pragma unroll
        for (int o = 1; o < 64; o <<= 1) {
            int t = __shfl_up(v, o);
            if (l64 >= o) v += t;
        }
        st[tid] = v;
        if (l64 == 63) stot[tid >> 6] = v;
    }
    __syncthreads();
    if (tid >= 64 && tid < 128) st[tid] += stot[0];
    __syncthreads();
    for (int i = tid; i < TOT; i += 256) {
        int s = i / REG_, j = i - s * REG_;
        if (j < cnt_s[s]) {
            unsigned pk = bl[i];
            int dl = (int)(pk >> 12);
            int p = st[dl] - cnt[dl] + atomicAdd(&cur[dl], 1);
            sorted[p] = (unsigned short)(pk & 0xFFFu);
        }
    }
    __syncthreads();
    int n = st[127];
    for (int i = tid; i < n; i += 256) blist[bb + i] = ((unsigned int)sorted[i]) << 5;
    int lo = ch * LSTR;
    int nloc = min(LSTR, NL - lo);
    int gbase = g * NL;
    if (tid < nloc) {
        int node = gbase + lo + tid;
        int c = cnt[tid];
        int start = (int)bb + st[tid] - c;
        ninfo[node] = (start << 8) | min(c, 255);
        rsqv[tid] = rsqrtf((float)(c + 1));
    }
    __syncthreads();
    for (int idx = tid; idx < nloc * 32; idx += 256) {
        int nl = idx >> 5, f2 = idx & 31;
        int node = gbase + lo + nl;
        float sc = rsqv[nl];
        float2 v;
        if (STAGE == 1) v = ((const float2*)xf)[(size_t)node * 32 + f2];
        else            v = bf2f(xg[(size_t)node * 32 + f2]);
        xb[(size_t)node * 32 + f2] = f2bf(v.x * sc, v.y * sc);
    }
}

// ---------------- gather-aggregate over pre-scaled bf16 rows (R14-proven form) --------------
template<bool GATE>
__launch_bounds__(256)
__global__ void k_agg(const unsigned int* xb, const int* ninfo, const unsigned int* csr,
                      float* y) {
    int b = blockIdx.x;
    int xcd = b & 7, r = b >> 3;
    int graph, local;
    if (GATE) {
        graph = xcd * 8 + r / 410;            // ceil(1639/4)=410 blocks/graph
        local = (r % 410) * 4 + (threadIdx.x >> 6);
        if (local >= K1_) return;
    } else {
        graph = xcd * 8 + (r >> 9);           // 512 blocks/graph
        local = (r & 511) * 4 + (threadIdx.x >> 6);
    }
    const int NL = GATE ? K1_ : N_;
    int node = graph * NL + local;
    int lane = threadIdx.x & 63;
    int half = lane >> 5;
    int fpos = lane & 31;
    int ni = ninfo[node];
    int cnt = ni & 255, base = ni >> 8;
    float rd = rsqrtf((float)(cnt + 1));
    float ax = 0.f, ay = 0.f, bx = 0.f, by = 0.f;
    float cx = 0.f, cy = 0.f, dx = 0.f, dy = 0.f;
    int gbase32 = graph * NL * 32;
    for (int chunk = 0; chunk < cnt; chunk += 64) {
        int nch = min(64, cnt - chunk);
        int sv = 0;
        if (lane < nch) sv = gbase32 + (int)csr[base + chunk + lane];
        int i = 0;
        for (; i + 8 <= nch; i += 8) {
            int s0 = __shfl(sv, i + half),     s1 = __shfl(sv, i + 2 + half),
                s2 = __shfl(sv, i + 4 + half), s3 = __shfl(sv, i + 6 + half);
            unsigned u0 = xb[(size_t)(s0 + fpos)];
            unsigned u1 = xb[(size_t)(s1 + fpos)];
            unsigned u2 = xb[(size_t)(s2 + fpos)];
            unsigned u3 = xb[(size_t)(s3 + fpos)];
            float2 f0 = bf2f(u0), f1 = bf2f(u1), f2 = bf2f(u2), f3 = bf2f(u3);
            ax += f0.x; ay += f0.y;
            bx += f1.x; by += f1.y;
            cx += f2.x; cy += f2.y;
            dx += f3.x; dy += f3.y;
        }
        for (; i + 4 <= nch; i += 4) {
            int s0 = __shfl(sv, i + half), s1 = __shfl(sv, i + 2 + half);
            float2 f0 = bf2f(xb[(size_t)(s0 + fpos)]);
            float2 f1 = bf2f(xb[(size_t)(s1 + fpos)]);
            ax += f0.x; ay += f0.y;
            bx += f1.x; by += f1.y;
        }
        for (; i < nch; i += 2) {
            int idx = i + half;
            int s0 = __shfl(sv, idx & 63);
            float m = (idx < nch) ? 1.f : 0.f;
            float2 f0 = bf2f(xb[(size_t)(s0 + fpos)]);
            ax += f0.x * m; ay += f0.y * m;
        }
    }
    float sx = (ax + bx) + (cx + dx), sy = (ay + by) + (cy + dy);
    sx += __shfl(sx, lane ^ 32);
    sy += __shfl(sy, lane ^ 32);
    if (half == 0) {
        float2 fs = bf2f(xb[(size_t)node * 32 + fpos]);   // pre-scaled self row
        float2 o;
        o.x = (sx + fs.x) * rd;
        o.y = (sy + fs.y) * rd;
        ((float2*)y)[(size_t)node * 32 + fpos] = o;
    }
}

// ---------------- MFMA conv: conv = relu(y @ W + b), score = tanh(conv.p/||p||) ------------
__launch_bounds__(256)
__global__ void k_convrow(float* y, const float* W, const float* bias, const float* pvec,
                          float* score, int rows) {
    int wid  = threadIdx.x >> 6;
    int lane = threadIdx.x & 63;
    int rowbase = blockIdx.x * 64 + wid * 16;
    int q = lane >> 4, c = lane & 15;
    bf8 bh[2][4], blo[2][4];
#pragma unroll
    for (int ks = 0; ks < 2; ks++)
#pragma unroll
        for (int nt = 0; nt < 4; nt++) {
            bf8 h, l;
#pragma unroll
            for (int j = 0; j < 8; j++) {
                float wv = W[(ks * 32 + q * 8 + j) * 64 + nt * 16 + c];
                unsigned short hb = f2bf_rn(wv);
                h[j] = (short)hb;
                l[j] = (short)f2bf_rn(wv - __uint_as_float((unsigned)hb << 16));
            }
            bh[ks][nt] = h; blo[ks][nt] = l;
        }
    const float* yr = y + (size_t)(rowbase + c) * DIM_ + q * 8;
    bf8 ah[2], al[2];
#pragma unroll
    for (int ks = 0; ks < 2; ks++) {
        float4 v0 = *(const float4*)(yr + ks * 32);
        float4 v1 = *(const float4*)(yr + ks * 32 + 4);
        float vv[8] = {v0.x, v0.y, v0.z, v0.w, v1.x, v1.y, v1.z, v1.w};
        bf8 h, l;
#pragma unroll
        for (int j = 0; j < 8; j++) {
            unsigned short hb = f2bf_rn(vv[j]);
            h[j] = (short)hb;
            l[j] = (short)f2bf_rn(vv[j] - __uint_as_float((unsigned)hb << 16));
        }
        ah[ks] = h; al[ks] = l;
    }
    float pp = 0.f;
#pragma unroll
    for (int i = 0; i < DIM_; i++) pp += pvec[i] * pvec[i];
    float rpn = rsqrtf(pp);
    float dot[4] = {0.f, 0.f, 0.f, 0.f};
#pragma unroll
    for (int nt = 0; nt < 4; nt++) {
        f4 acc = {0.f, 0.f, 0.f, 0.f};
#pragma unroll
        for (int ks = 0; ks < 2; ks++) {
            acc = __builtin_amdgcn_mfma_f32_16x16x32_bf16(ah[ks], bh[ks][nt],  acc, 0, 0, 0);
            acc = __builtin_amdgcn_mfma_f32_16x16x32_bf16(ah[ks], blo[ks][nt], acc, 0, 0, 0);
            acc = __builtin_amdgcn_mfma_f32_16x16x32_bf16(al[ks], bh[ks][nt],  acc, 0, 0, 0);
        }
        float bcol = bias[nt * 16 + c];
        float pcol = pvec[nt * 16 + c];
        float st[4];
#pragma unroll
        for (int reg = 0; reg < 4; reg++) {
            float v = fmaxf(acc[reg] + bcol, 0.f);
            st[reg] = v;
            dot[reg] += v * pcol;
        }
#pragma unroll
        for (int reg = 0; reg < 4; reg++)
            y[(size_t)(rowbase + q * 4 + reg) * DIM_ + nt * 16 + c] = st[reg];
    }
#pragma unroll
    for (int m = 1; m < 16; m <<= 1) {
#pragma unroll
        for (int reg = 0; reg < 4; reg++) dot[reg] += __shfl_xor(dot[reg], m);
    }
    if (c == 0) {
#pragma unroll
        for (int reg = 0; reg < 4; reg++)
            score[rowbase + q * 4 + reg] = tanhf(dot[reg] * rpn);
    }
    (void)rows;
}

// ---------------- FUSED select + pool (+ head in stage 2), one block per graph --------------
// Phase A: exact 6-pass radix select (bins/scan on first 256 threads).
// Phase B: kept (idx,score) list in LDS; 16 waves pool K rows (lane=feature).
// STAGE1: writes new_id, xg (gated bf16 rows, slot order), x1=[max|mean].
// STAGE2: computes h = x1 + [max|mean], runs the MLP head, writes logits.
template<int STAGE>
__launch_bounds__(1024)
__global__ void k_selpool(const float* score, const float* conv, int* new_id,
                          unsigned int* xg, float* x1,
                          const float* l1w, const float* l1b,
                          const float* l2w, const float* l2b, float* out) {
    const int Nin = (STAGE == 1) ? N_ : K1_;
    const int K   = (STAGE == 1) ? K1_ : K2_;
    __shared__ unsigned long long keys[N_];
    __shared__ int bins[256], ts[256], wsum[4];
    __shared__ unsigned long long s_prefix;
    __shared__ int s_need, s_cnt;
    __shared__ int   lidx[K1_];
    __shared__ float lval[K1_];
    __shared__ float rmx[16][64], rsm[16][64];
    __shared__ float hh[128], h1[64];
    int g = blockIdx.x, tid = threadIdx.x;
    int wv = tid >> 6, lane = tid & 63;
    const float* sg = score + (size_t)g * Nin;
    for (int i = tid; i < N_; i += 1024) {
        unsigned long long key = 0ull;
        if (i < Nin) {
            unsigned u = __float_as_uint(sg[i]);
            u = (u & 0x80000000u) ? ~u : (u | 0x80000000u);
            key = ((unsigned long long)u << 11) | (unsigned long long)(2047 - i);
        }
        keys[i] = key;
    }
    if (tid == 0) { s_need = K; s_prefix = 0ull; s_cnt = 0; }
    if (tid < 256) bins[tid] = 0;
    __syncthreads();
    for (int shift = 40; shift >= 0; shift -= 8) {
        unsigned long long pref = s_prefix;
        int need = s_need;
        int hi = shift + 8;
        for (int i = tid; i < Nin; i += 1024) {
            unsigned long long k = keys[i];
            if ((k >> hi) == pref) atomicAdd(&bins[(int)((k >> shift) & 255)], 1);
        }
        __syncthreads();
        if (tid < 256) {
            int v = bins[tid];
            int l = tid & 63;
#pragma unroll
            for (int o = 1; o < 64; o <<= 1) {       // wave suffix scan
                int t = __shfl_down(v, o);
                if (l + o < 64) v += t;
            }
            ts[tid] = v;
            if (l == 0) wsum[tid >> 6] = v;
        }
        __syncthreads();
        if (tid < 256) {
            int mine = bins[tid];
            int v = ts[tid];
            for (int w = (tid >> 6) + 1; w < 4; w++) v += wsum[w];
            int nxt = v - mine;
            if (v >= need && nxt < need) {            // exactly one tid matches
                s_prefix = (pref << 8) | (unsigned long long)tid;
                s_need = need - nxt;
            }
        }
        __syncthreads();
        if (tid < 256) bins[tid] = 0;                 // re-zero for next pass
        __syncthreads();
    }
    unsigned long long T = s_prefix;
    for (int i = tid; i < Nin; i += 1024) {
        bool keep = keys[i] >= T;
        int r = -1;
        if (keep) {
            r = atomicAdd(&s_cnt, 1);
            lidx[r] = i;
            lval[r] = sg[i];
        }
        if (STAGE == 1) new_id[g * N_ + i] = keep ? (g * K1_ + r) : -1;
    }
    __syncthreads();
    // ---- pool over the kept list; wave per row, lane == feature ----
    float mx = -3.402823466e38f, sm = 0.f;
    for (int r = wv; r < K; r += 16) {
        int row = g * Nin + lidx[r];
        float val = lval[r];
        float v = conv[(size_t)row * DIM_ + lane] * val;
        mx = fmaxf(mx, v);
        sm += v;
        if (STAGE == 1) {
            unsigned pk = f2bf(v, __shfl_xor(v, 1));
            if (!(lane & 1)) xg[((size_t)(g * K1_ + r)) * 32 + (lane >> 1)] = pk;
        }
    }
    rmx[wv][lane] = mx; rsm[wv][lane] = sm;
    __syncthreads();
    if (wv == 0) {
        mx = rmx[0][lane]; sm = rsm[0][lane];
#pragma unroll
        for (int w = 1; w < 16; w++) { mx = fmaxf(mx, rmx[w][lane]); sm += rsm[w][lane]; }
        if (STAGE == 1) {
            x1[g * 128 + lane]      = mx;
            x1[g * 128 + 64 + lane] = sm / (float)K1_;
        } else {
            hh[lane]      = x1[g * 128 + lane] + mx;
            hh[64 + lane] = x1[g * 128 + 64 + lane] + sm / (float)K2_;
        }
    }
    if (STAGE == 2) {
        __syncthreads();
        if (wv == 0) {
            float acc = l1b[lane];
#pragma unroll 8
            for (int i = 0; i < 128; i++) acc += hh[i] * l1w[i * 64 + lane];
            h1[lane] = fmaxf(acc, 0.0f);
        }
        __syncthreads();
        if (wv == 0 && lane < NCLS) {
            float o = l2b[lane];
#pragma unroll
            for (int i = 0; i < 64; i++) o += h1[i] * l2w[i * NCLS + lane];
            out[g * NCLS + lane] = o;
        }
    }
}

extern "C" void kernel_launch(void* const* d_in, const int* in_sizes, int n_in,
                              void* d_out, int out_size, void* d_ws, size_t ws_size,
                              hipStream_t stream) {
    const float* x   = (const float*)d_in[0];
    const int*   ei  = (const int*)d_in[1];
    const int*   src = ei;
    const int*   dst = ei + ETOT;
    const float* W1  = (const float*)d_in[3];
    const float* b1  = (const float*)d_in[4];
    const float* p1  = (const float*)d_in[5];
    const float* W2  = (const float*)d_in[6];
    const float* b2  = (const float*)d_in[7];
    const float* p2  = (const float*)d_in[8];
    const float* l1w = (const float*)d_in[9];
    const float* l1b = (const float*)d_in[10];
    const float* l2w = (const float*)d_in[11];
    const float* l2b = (const float*)d_in[12];
    (void)in_sizes; (void)n_in; (void)out_size; (void)ws_size;

    // workspace layout (~92 MB); xg aliases bufB (dead until agg2 writes it)
    char* ws = (char*)d_ws;
    size_t off = 0;
    auto alloc = [&](size_t bytes) -> void* {
        void* p = ws + off;
        off = (off + bytes + 255) & ~(size_t)255;
        return p;
    };
    float*        bufA  = (float*)       alloc((size_t)NTOT  * DIM_ * 4);  // y1 -> conv1
    float*        bufB  = (float*)       alloc((size_t)N2TOT * DIM_ * 4);  // xg, then y2 -> conv2
    unsigned int* blist = (unsigned int*)alloc((size_t)B_ * CHUNKS_ * BCAP * 4); // buckets -> csr
    unsigned int* xb    = (unsigned int*)alloc((size_t)NTOT * 32 * 4);     // bf16 prescaled rows
    int*          bcnt  = (int*)         alloc((size_t)B_ * SLICES_ * CHUNKS_ * 4);
    int*          ninfo = (int*)         alloc((size_t)NTOT * 4);
    float*        score = (float*)       alloc((size_t)NTOT * 4);
    int*          newid = (int*)         alloc((size_t)NTOT * 4);
    float*        x1    = (float*)       alloc((size_t)B_ * 128 * 4);
    unsigned int* xg    = (unsigned int*)bufB;   // alias: gated bf16 rows, consumed by sort2

    // ---- stage 1 ----
    k_bucket<1><<<B_ * SLICES_, 256, 0, stream>>>(src, dst, nullptr, bcnt, blist);
    k_sort<1><<<B_ * CHUNKS_, 256, 0, stream>>>(bcnt, blist, x, nullptr, xb, ninfo);
    k_agg<false><<<NTOT / 4, 256, 0, stream>>>(xb, ninfo, blist, bufA);
    k_convrow<<<NTOT / 64, 256, 0, stream>>>(bufA, W1, b1, p1, score, NTOT);
    k_selpool<1><<<B_, 1024, 0, stream>>>(score, bufA, newid, xg, x1,
                                          nullptr, nullptr, nullptr, nullptr, nullptr);

    // ---- stage 2 ----
    k_bucket<2><<<B_ * SLICES_, 256, 0, stream>>>(src, dst, newid, bcnt, blist);
    k_sort<2><<<B_ * CHUNKS_, 256, 0, stream>>>(bcnt, blist, nullptr, xg, xb, ninfo);
    k_agg<true><<<410 * B_, 256, 0, stream>>>(xb, ninfo, blist, bufB);
    k_convrow<<<N2TOT / 64, 256, 0, stream>>>(bufB, W2, b2, p2, score, N2TOT);
    k_selpool<2><<<B_, 1024, 0, stream>>>(score, bufB, nullptr, nullptr, x1,
                                          l1w, l1b, l2w, l2b, (float*)d_out);
}

// Round 18
// 335.945 us; speedup vs baseline: 1.1425x; 1.0407x over previous
//
#include <hip/hip_runtime.h>
#include <hip/hip_bf16.h>
#include <cstdint>
#include <cstddef>

#define B_    64
#define N_    2048
#define E_    32768            // edges per graph
#define DIM_  64
#define K1_   1639
#define K2_   1312
#define NTOT  (B_ * N_)        // 131072
#define ETOT  (B_ * E_)        // 2097152
#define N2TOT (B_ * K1_)       // 104896
#define NCLS  6
#define PB_   8                // selpool blocks per graph (index-partitioned)
#define CHUNKS_ 16             // dst-chunks per graph
#define SLICES_ 16             // edge slices per graph in k_bucket
#define BCAP  3072             // bucket capacity (= SLICES_*REG_)
#define REG_  192              // per-slice region (mean 128, sd ~11 -> +5.8 sigma)

typedef short bf8 __attribute__((ext_vector_type(8)));
typedef float f4  __attribute__((ext_vector_type(4)));

static __device__ __forceinline__ float2 bf2f(unsigned u) {
    float2 r;
    r.x = __uint_as_float(u << 16);
    r.y = __uint_as_float(u & 0xFFFF0000u);
    return r;
}
static __device__ __forceinline__ unsigned f2bf(float a, float b) {
    __hip_bfloat162 h = __float22bfloat162_rn(make_float2(a, b));
    unsigned u;
    __builtin_memcpy(&u, &h, 4);
    return u;
}
static __device__ __forceinline__ unsigned short f2bf_rn(float v) {
    unsigned u = __float_as_uint(v);
    return (unsigned short)((u + 0x7FFFu + ((u >> 16) & 1u)) >> 16);
}

// ---------------- bucket edges by (graph, dst-chunk) into slice-owned regions --------------
template<int STAGE>
__launch_bounds__(256)
__global__ void k_bucket(const int* src, const int* dst, const int* remap,
                         int* bcnt, unsigned int* blist) {
    const int LSTR = (STAGE == 1) ? 128 : 103;
    __shared__ unsigned int lb[CHUNKS_][REG_];
    __shared__ int lc[CHUNKS_];
    __shared__ int rm[N_];                     // stage2 only
    int b = blockIdx.x;
    int g = b & 63, slice = b >> 6;
    int tid = threadIdx.x;
    if (tid < CHUNKS_) lc[tid] = 0;
    if (STAGE == 2)
        for (int i = tid; i < N_; i += 256) rm[i] = remap[g * N_ + i];
    __syncthreads();
    const int ESL = E_ / SLICES_;              // 2048
    const int* sp = src + (size_t)g * E_ + slice * ESL;
    const int* dp = dst + (size_t)g * E_ + slice * ESL;
    int gbase = g * ((STAGE == 1) ? N_ : K1_);
    for (int e = tid * 4; e < ESL; e += 1024) {
        int4 ss = *(const int4*)&sp[e];
        int4 dd = *(const int4*)&dp[e];
#pragma unroll
        for (int t = 0; t < 4; t++) {
            int s = (&ss.x)[t], d = (&dd.x)[t];
            if (STAGE == 2) {
                s = rm[s & (N_ - 1)]; d = rm[d & (N_ - 1)];
                if ((s | d) < 0) continue;     // edge touches a dropped node
                s -= gbase; d -= gbase;
            } else {
                s &= (N_ - 1); d &= (N_ - 1);
            }
            int ch = d / LSTR;
            int dl = d - ch * LSTR;
            int p = atomicAdd(&lc[ch], 1);
            if (p < REG_) lb[ch][p] = ((unsigned)dl << 12) | (unsigned)s;
        }
    }
    __syncthreads();
    for (int ch = 0; ch < CHUNKS_; ch++) {
        int n = min(lc[ch], REG_);
        unsigned int* out = blist + (size_t)(g * CHUNKS_ + ch) * BCAP + slice * REG_;
        for (int i = tid; i < n; i += 256) out[i] = lb[ch][i];
    }
    if (tid < CHUNKS_) bcnt[(g * SLICES_ + slice) * CHUNKS_ + tid] = min(lc[tid], REG_);
}

// ---------------- counting-sort -> in-place compact CSR (pre-shifted) + ninfo + prescale ----
template<int STAGE>
__launch_bounds__(256)
__global__ void k_sort(const int* bcnt, unsigned int* blist,
                       const float* xf, const unsigned int* xg,
                       unsigned int* xb, int* ninfo) {
    const int NL   = (STAGE == 1) ? N_ : K1_;
    const int LSTR = (STAGE == 1) ? 128 : 103;
    __shared__ int cnt[128], st[128], cur[128], cnt_s[SLICES_], stot[2];
    __shared__ float rsqv[128];
    __shared__ unsigned short sorted[BCAP];
    int b = blockIdx.x;
    int g = b & 63, ch = b >> 6;
    int tid = threadIdx.x;
    if (tid < 128) { cnt[tid] = 0; cur[tid] = 0; }
    if (tid < SLICES_) cnt_s[tid] = bcnt[(g * SLICES_ + tid) * CHUNKS_ + ch];
    __syncthreads();
    size_t bb = (size_t)(g * CHUNKS_ + ch) * BCAP;
    const unsigned int* bl = blist + bb;
    const int TOT = SLICES_ * REG_;            // 3072
    for (int i = tid; i < TOT; i += 256) {
        int s = i / REG_, j = i - s * REG_;
        if (j < cnt_s[s]) atomicAdd(&cnt[bl[i] >> 12], 1);
    }
    __syncthreads();
    if (tid < 128) {
        int v = cnt[tid];
        int l64 = tid & 63;
#pragma unroll
        for (int o = 1; o < 64; o <<= 1) {
            int t = __shfl_up(v, o);
            if (l64 >= o) v += t;
        }
        st[tid] = v;
        if (l64 == 63) stot[tid >> 6] = v;
    }
    __syncthreads();
    if (tid >= 64 && tid < 128) st[tid] += stot[0];
    __syncthreads();
    for (int i = tid; i < TOT; i += 256) {
        int s = i / REG_, j = i - s * REG_;
        if (j < cnt_s[s]) {
            unsigned pk = bl[i];
            int dl = (int)(pk >> 12);
            int p = st[dl] - cnt[dl] + atomicAdd(&cur[dl], 1);
            sorted[p] = (unsigned short)(pk & 0xFFFu);
        }
    }
    __syncthreads();
    int n = st[127];
    for (int i = tid; i < n; i += 256) blist[bb + i] = ((unsigned int)sorted[i]) << 5;
    int lo = ch * LSTR;
    int nloc = min(LSTR, NL - lo);
    int gbase = g * NL;
    if (tid < nloc) {
        int node = gbase + lo + tid;
        int c = cnt[tid];
        int start = (int)bb + st[tid] - c;
        ninfo[node] = (start << 8) | min(c, 255);
        rsqv[tid] = rsqrtf((float)(c + 1));
    }
    __syncthreads();
    for (int idx = tid; idx < nloc * 32; idx += 256) {
        int nl = idx >> 5, f2 = idx & 31;
        int node = gbase + lo + nl;
        float sc = rsqv[nl];
        float2 v;
        if (STAGE == 1) v = ((const float2*)xf)[(size_t)node * 32 + f2];
        else            v = bf2f(xg[(size_t)node * 32 + f2]);
        xb[(size_t)node * 32 + f2] = f2bf(v.x * sc, v.y * sc);
    }
}

// ---------------- gather-aggregate over pre-scaled bf16 rows (R14-proven form) --------------
template<bool GATE>
__launch_bounds__(256)
__global__ void k_agg(const unsigned int* xb, const int* ninfo, const unsigned int* csr,
                      float* y) {
    int b = blockIdx.x;
    int xcd = b & 7, r = b >> 3;
    int graph, local;
    if (GATE) {
        graph = xcd * 8 + r / 410;            // ceil(1639/4)=410 blocks/graph
        local = (r % 410) * 4 + (threadIdx.x >> 6);
        if (local >= K1_) return;
    } else {
        graph = xcd * 8 + (r >> 9);           // 512 blocks/graph
        local = (r & 511) * 4 + (threadIdx.x >> 6);
    }
    const int NL = GATE ? K1_ : N_;
    int node = graph * NL + local;
    int lane = threadIdx.x & 63;
    int half = lane >> 5;
    int fpos = lane & 31;
    int ni = ninfo[node];
    int cnt = ni & 255, base = ni >> 8;
    float rd = rsqrtf((float)(cnt + 1));
    float ax = 0.f, ay = 0.f, bx = 0.f, by = 0.f;
    float cx = 0.f, cy = 0.f, dx = 0.f, dy = 0.f;
    int gbase32 = graph * NL * 32;
    for (int chunk = 0; chunk < cnt; chunk += 64) {
        int nch = min(64, cnt - chunk);
        int sv = 0;
        if (lane < nch) sv = gbase32 + (int)csr[base + chunk + lane];
        int i = 0;
        for (; i + 8 <= nch; i += 8) {
            int s0 = __shfl(sv, i + half),     s1 = __shfl(sv, i + 2 + half),
                s2 = __shfl(sv, i + 4 + half), s3 = __shfl(sv, i + 6 + half);
            unsigned u0 = xb[(size_t)(s0 + fpos)];
            unsigned u1 = xb[(size_t)(s1 + fpos)];
            unsigned u2 = xb[(size_t)(s2 + fpos)];
            unsigned u3 = xb[(size_t)(s3 + fpos)];
            float2 f0 = bf2f(u0), f1 = bf2f(u1), f2 = bf2f(u2), f3 = bf2f(u3);
            ax += f0.x; ay += f0.y;
            bx += f1.x; by += f1.y;
            cx += f2.x; cy += f2.y;
            dx += f3.x; dy += f3.y;
        }
        for (; i + 4 <= nch; i += 4) {
            int s0 = __shfl(sv, i + half), s1 = __shfl(sv, i + 2 + half);
            float2 f0 = bf2f(xb[(size_t)(s0 + fpos)]);
            float2 f1 = bf2f(xb[(size_t)(s1 + fpos)]);
            ax += f0.x; ay += f0.y;
            bx += f1.x; by += f1.y;
        }
        for (; i < nch; i += 2) {
            int idx = i + half;
            int s0 = __shfl(sv, idx & 63);
            float m = (idx < nch) ? 1.f : 0.f;
            float2 f0 = bf2f(xb[(size_t)(s0 + fpos)]);
            ax += f0.x * m; ay += f0.y * m;
        }
    }
    float sx = (ax + bx) + (cx + dx), sy = (ay + by) + (cy + dy);
    sx += __shfl(sx, lane ^ 32);
    sy += __shfl(sy, lane ^ 32);
    if (half == 0) {
        float2 fs = bf2f(xb[(size_t)node * 32 + fpos]);   // pre-scaled self row
        float2 o;
        o.x = (sx + fs.x) * rd;
        o.y = (sy + fs.y) * rd;
        ((float2*)y)[(size_t)node * 32 + fpos] = o;
    }
}

// ---------------- MFMA conv: conv = relu(y @ W + b), score = tanh(conv.p/||p||) ------------
__launch_bounds__(256)
__global__ void k_convrow(float* y, const float* W, const float* bias, const float* pvec,
                          float* score, int rows) {
    int wid  = threadIdx.x >> 6;
    int lane = threadIdx.x & 63;
    int rowbase = blockIdx.x * 64 + wid * 16;
    int q = lane >> 4, c = lane & 15;
    bf8 bh[2][4], blo[2][4];
#pragma unroll
    for (int ks = 0; ks < 2; ks++)
#pragma unroll
        for (int nt = 0; nt < 4; nt++) {
            bf8 h, l;
#pragma unroll
            for (int j = 0; j < 8; j++) {
                float wv = W[(ks * 32 + q * 8 + j) * 64 + nt * 16 + c];
                unsigned short hb = f2bf_rn(wv);
                h[j] = (short)hb;
                l[j] = (short)f2bf_rn(wv - __uint_as_float((unsigned)hb << 16));
            }
            bh[ks][nt] = h; blo[ks][nt] = l;
        }
    const float* yr = y + (size_t)(rowbase + c) * DIM_ + q * 8;
    bf8 ah[2], al[2];
#pragma unroll
    for (int ks = 0; ks < 2; ks++) {
        float4 v0 = *(const float4*)(yr + ks * 32);
        float4 v1 = *(const float4*)(yr + ks * 32 + 4);
        float vv[8] = {v0.x, v0.y, v0.z, v0.w, v1.x, v1.y, v1.z, v1.w};
        bf8 h, l;
#pragma unroll
        for (int j = 0; j < 8; j++) {
            unsigned short hb = f2bf_rn(vv[j]);
            h[j] = (short)hb;
            l[j] = (short)f2bf_rn(vv[j] - __uint_as_float((unsigned)hb << 16));
        }
        ah[ks] = h; al[ks] = l;
    }
    float pp = 0.f;
#pragma unroll
    for (int i = 0; i < DIM_; i++) pp += pvec[i] * pvec[i];
    float rpn = rsqrtf(pp);
    float dot[4] = {0.f, 0.f, 0.f, 0.f};
#pragma unroll
    for (int nt = 0; nt < 4; nt++) {
        f4 acc = {0.f, 0.f, 0.f, 0.f};
#pragma unroll
        for (int ks = 0; ks < 2; ks++) {
            acc = __builtin_amdgcn_mfma_f32_16x16x32_bf16(ah[ks], bh[ks][nt],  acc, 0, 0, 0);
            acc = __builtin_amdgcn_mfma_f32_16x16x32_bf16(ah[ks], blo[ks][nt], acc, 0, 0, 0);
            acc = __builtin_amdgcn_mfma_f32_16x16x32_bf16(al[ks], bh[ks][nt],  acc, 0, 0, 0);
        }
        float bcol = bias[nt * 16 + c];
        float pcol = pvec[nt * 16 + c];
        float st[4];
#pragma unroll
        for (int reg = 0; reg < 4; reg++) {
            float v = fmaxf(acc[reg] + bcol, 0.f);
            st[reg] = v;
            dot[reg] += v * pcol;
        }
#pragma unroll
        for (int reg = 0; reg < 4; reg++)
            y[(size_t)(rowbase + q * 4 + reg) * DIM_ + nt * 16 + c] = st[reg];
    }
#pragma unroll
    for (int m = 1; m < 16; m <<= 1) {
#pragma unroll
        for (int reg = 0; reg < 4; reg++) dot[reg] += __shfl_xor(dot[reg], m);
    }
    if (c == 0) {
#pragma unroll
        for (int reg = 0; reg < 4; reg++)
            score[rowbase + q * 4 + reg] = tanhf(dot[reg] * rpn);
    }
    (void)rows;
}

// ---------------- FUSED select + pool, PB_ blocks per graph, 256 threads ----------------
// Each block redundantly runs the 6-pass radix select (parallel wall-time), computes
// DETERMINISTIC ranks (prefix count of kept indices -- any consistent bijection is
// output-invariant), then pools only its 1/PB_ index range. STAGE1 also writes new_id
// (its range) and xg rows (rank slots). Partials go to part[] for k_head to combine.
template<int STAGE>
__launch_bounds__(256)
__global__ void k_selpool(const float* score, const float* conv, int* new_id,
                          unsigned int* xg, float* part) {
    const int Nin = (STAGE == 1) ? N_ : K1_;
    const int K   = (STAGE == 1) ? K1_ : K2_;
    const int RNG = (STAGE == 1) ? (N_ / PB_) : ((K1_ + PB_ - 1) / PB_);  // 256 / 205
    __shared__ unsigned long long keys[N_];
    __shared__ int bins[256], wsum[4];
    __shared__ unsigned long long s_prefix;
    __shared__ int s_need;
    __shared__ int rnk[N_];
    __shared__ float rmx[4][64], rsm[4][64];
    int b = blockIdx.x;
    int g = b & 63, pb = b >> 6;               // graph (XCD affinity), part index
    int tid = threadIdx.x;
    int l64 = tid & 63, wid = tid >> 6;
    const float* sg = score + (size_t)g * Nin;
    for (int i = tid; i < N_; i += 256) {
        unsigned long long key = 0ull;         // padding sorts last (real keys > 0)
        if (i < Nin) {
            unsigned u = __float_as_uint(sg[i]);
            u = (u & 0x80000000u) ? ~u : (u | 0x80000000u);
            key = ((unsigned long long)u << 11) | (unsigned long long)(2047 - i);
        }
        keys[i] = key;
    }
    if (tid == 0) { s_need = K; s_prefix = 0ull; }
    __syncthreads();
    for (int shift = 40; shift >= 0; shift -= 8) {
        bins[tid] = 0;
        __syncthreads();
        unsigned long long pref = s_prefix;
        int need = s_need;
        int hi = shift + 8;
        for (int i = tid; i < Nin; i += 256) {
            unsigned long long k = keys[i];
            if ((k >> hi) == pref) atomicAdd(&bins[(int)((k >> shift) & 255)], 1);
        }
        __syncthreads();
        int mine = bins[tid];
        int v = mine;
#pragma unroll
        for (int o = 1; o < 64; o <<= 1) {     // wave suffix scan
            int t = __shfl_down(v, o);
            if (l64 + o < 64) v += t;
        }
        if (l64 == 0) wsum[wid] = v;
        __syncthreads();
        for (int w = wid + 1; w < 4; w++) v += wsum[w];
        int nxt = v - mine;
        if (v >= need && nxt < need) {         // exactly one tid matches
            s_prefix = (pref << 8) | (unsigned long long)tid;
            s_need = need - nxt;
        }
        __syncthreads();
    }
    unsigned long long T = s_prefix;           // exact K-th largest key
    if (STAGE == 1) {
        // deterministic rank = prefix count of keep-mask (8 keys per thread)
        int base8 = tid * 8;
        int loc[8];
        int c8 = 0;
#pragma unroll
        for (int j = 0; j < 8; j++) { loc[j] = c8; c8 += (keys[base8 + j] >= T) ? 1 : 0; }
        int v = c8;
#pragma unroll
        for (int o = 1; o < 64; o <<= 1) {     // inclusive wave scan
            int t = __shfl_up(v, o);
            if (l64 >= o) v += t;
        }
        if (l64 == 63) wsum[wid] = v;
        __syncthreads();
        int wbase = 0;
        for (int w = 0; w < wid; w++) wbase += wsum[w];
        int exc = wbase + v - c8;
#pragma unroll
        for (int j = 0; j < 8; j++) rnk[base8 + j] = exc + loc[j];
        __syncthreads();
        // emit new_id for this block's index range (one element per thread)
        int i = pb * RNG + tid;
        bool keep = keys[i] >= T;
        new_id[g * N_ + i] = keep ? (g * K1_ + rnk[i]) : -1;
    }
    // ---- pool this block's index range; wave per node, lane == feature ----
    int R0 = pb * RNG;
    int R1 = min(R0 + RNG, Nin);
    float mx = -3.402823466e38f, sm = 0.f;
    for (int i = R0 + wid; i < R1; i += 4) {
        if (keys[i] < T) continue;             // wave-uniform branch
        float val = sg[i];
        float v = conv[(size_t)(g * Nin + i) * DIM_ + l64] * val;
        mx = fmaxf(mx, v);
        sm += v;
        if (STAGE == 1) {
            unsigned pk = f2bf(v, __shfl_xor(v, 1));
            if (!(l64 & 1)) xg[(size_t)(g * K1_ + rnk[i]) * 32 + (l64 >> 1)] = pk;
        }
    }
    rmx[wid][l64] = mx; rsm[wid][l64] = sm;
    __syncthreads();
    if (wid == 0) {
        mx = fmaxf(fmaxf(rmx[0][l64], rmx[1][l64]), fmaxf(rmx[2][l64], rmx[3][l64]));
        sm = rsm[0][l64] + rsm[1][l64] + rsm[2][l64] + rsm[3][l64];
        part[((size_t)(g * PB_ + pb) * 2 + 0) * 64 + l64] = mx;
        part[((size_t)(g * PB_ + pb) * 2 + 1) * 64 + l64] = sm;
    }
}

// ---------------- MLP head (combines both stages' partials) ----------------
__launch_bounds__(64)
__global__ void k_head(const float* part1, const float* part2,
                       const float* l1w, const float* l1b,
                       const float* l2w, const float* l2b, float* out) {
    __shared__ float h[128];
    __shared__ float h1[64];
    int g = blockIdx.x, t = threadIdx.x;
    float mx1 = -3.402823466e38f, sm1 = 0.f, mx2 = -3.402823466e38f, sm2 = 0.f;
#pragma unroll
    for (int c = 0; c < PB_; c++) {
        mx1 = fmaxf(mx1, part1[((size_t)(g * PB_ + c) * 2 + 0) * 64 + t]);
        sm1 += part1[((size_t)(g * PB_ + c) * 2 + 1) * 64 + t];
        mx2 = fmaxf(mx2, part2[((size_t)(g * PB_ + c) * 2 + 0) * 64 + t]);
        sm2 += part2[((size_t)(g * PB_ + c) * 2 + 1) * 64 + t];
    }
    h[t]      = mx1 + mx2;
    h[t + 64] = sm1 / (float)K1_ + sm2 / (float)K2_;
    __syncthreads();
    float acc = l1b[t];
#pragma unroll 8
    for (int i = 0; i < 128; i++) acc += h[i] * l1w[i * 64 + t];
    h1[t] = fmaxf(acc, 0.0f);
    __syncthreads();
    if (t < NCLS) {
        float o = l2b[t];
#pragma unroll
        for (int i = 0; i < 64; i++) o += h1[i] * l2w[i * NCLS + t];
        out[g * NCLS + t] = o;
    }
}

extern "C" void kernel_launch(void* const* d_in, const int* in_sizes, int n_in,
                              void* d_out, int out_size, void* d_ws, size_t ws_size,
                              hipStream_t stream) {
    const float* x   = (const float*)d_in[0];
    const int*   ei  = (const int*)d_in[1];
    const int*   src = ei;
    const int*   dst = ei + ETOT;
    const float* W1  = (const float*)d_in[3];
    const float* b1  = (const float*)d_in[4];
    const float* p1  = (const float*)d_in[5];
    const float* W2  = (const float*)d_in[6];
    const float* b2  = (const float*)d_in[7];
    const float* p2  = (const float*)d_in[8];
    const float* l1w = (const float*)d_in[9];
    const float* l1b = (const float*)d_in[10];
    const float* l2w = (const float*)d_in[11];
    const float* l2b = (const float*)d_in[12];
    (void)in_sizes; (void)n_in; (void)out_size; (void)ws_size;

    // workspace layout (~92 MB); xg aliases bufB (dead until agg2 writes it)
    char* ws = (char*)d_ws;
    size_t off = 0;
    auto alloc = [&](size_t bytes) -> void* {
        void* p = ws + off;
        off = (off + bytes + 255) & ~(size_t)255;
        return p;
    };
    float*        bufA  = (float*)       alloc((size_t)NTOT  * DIM_ * 4);  // y1 -> conv1
    float*        bufB  = (float*)       alloc((size_t)N2TOT * DIM_ * 4);  // xg, then y2 -> conv2
    unsigned int* blist = (unsigned int*)alloc((size_t)B_ * CHUNKS_ * BCAP * 4); // buckets -> csr
    unsigned int* xb    = (unsigned int*)alloc((size_t)NTOT * 32 * 4);     // bf16 prescaled rows
    int*          bcnt  = (int*)         alloc((size_t)B_ * SLICES_ * CHUNKS_ * 4);
    int*          ninfo = (int*)         alloc((size_t)NTOT * 4);
    float*        score = (float*)       alloc((size_t)NTOT * 4);
    int*          newid = (int*)         alloc((size_t)NTOT * 4);
    float*        part1 = (float*)       alloc((size_t)B_ * PB_ * 128 * 4);
    float*        part2 = (float*)       alloc((size_t)B_ * PB_ * 128 * 4);
    unsigned int* xg    = (unsigned int*)bufB;   // alias: gated bf16 rows, consumed by sort2

    // ---- stage 1 ----
    k_bucket<1><<<B_ * SLICES_, 256, 0, stream>>>(src, dst, nullptr, bcnt, blist);
    k_sort<1><<<B_ * CHUNKS_, 256, 0, stream>>>(bcnt, blist, x, nullptr, xb, ninfo);
    k_agg<false><<<NTOT / 4, 256, 0, stream>>>(xb, ninfo, blist, bufA);
    k_convrow<<<NTOT / 64, 256, 0, stream>>>(bufA, W1, b1, p1, score, NTOT);
    k_selpool<1><<<B_ * PB_, 256, 0, stream>>>(score, bufA, newid, xg, part1);

    // ---- stage 2 ----
    k_bucket<2><<<B_ * SLICES_, 256, 0, stream>>>(src, dst, newid, bcnt, blist);
    k_sort<2><<<B_ * CHUNKS_, 256, 0, stream>>>(bcnt, blist, nullptr, xg, xb, ninfo);
    k_agg<true><<<410 * B_, 256, 0, stream>>>(xb, ninfo, blist, bufB);
    k_convrow<<<N2TOT / 64, 256, 0, stream>>>(bufB, W2, b2, p2, score, N2TOT);
    k_selpool<2><<<B_ * PB_, 256, 0, stream>>>(score, bufB, nullptr, nullptr, part2);

    // ---- head (combines both stages' partials) ----
    k_head<<<B_, 64, 0, stream>>>(part1, part2, l1w, l1b, l2w, l2b, (float*)d_out);
}